// Round 1
// baseline (107.299 us; speedup 1.0000x reference)
//
#include <hip/hip_runtime.h>
#include <stdint.h>

typedef _Float16 half8 __attribute__((ext_vector_type(8)));
typedef float f32x16 __attribute__((ext_vector_type(16)));

// ---------------- sizes ----------------
// F  : per-pixel-channel features, fp16. p = ((b*66+h)*66+w)*32 + c ; F[p*18 + m]
//      m=0..16 hat_m(clip(x)) on grid -1..1 (h=0.125), m=17 silu(x)
// th : theta^T fp16, [i(3)][f(64)][k(1728)], k = j*576 + c*18 + m
//      m<17: w_spline*cp[m] ; m==17: w_silu
#define NPX  (4 * 66 * 66 * 32)          // 557568
#define NTH  (3 * 64 * 1728)             // 331776
#define TH_OFF_BYTES ((size_t)NPX * 18 * 2)   // 20,072,448
#define PREP_BLOCKS  ((NPX + NTH) / 256)      // 3474 exactly

__global__ __launch_bounds__(256) void kan_prep(
    const float* __restrict__ x, const float* __restrict__ cp,
    const float* __restrict__ wspl, const float* __restrict__ wsil,
    _Float16* __restrict__ Ff, _Float16* __restrict__ th)
{
    int tid = blockIdx.x * 256 + threadIdx.x;
    if (tid < NPX) {
        float p  = x[tid];
        float xc = fminf(1.0f, fmaxf(-1.0f, p));
        float u  = fmaf(xc, 8.0f, 8.0f);                    // [0,16]
        union { _Float16 h[18]; uint32_t w[9]; } pk;
#pragma unroll
        for (int m = 0; m < 17; ++m)
            pk.h[m] = (_Float16)fmaxf(0.0f, 1.0f - fabsf(u - (float)m));
        pk.h[17] = (_Float16)(p * __builtin_amdgcn_rcpf(1.0f + __expf(-p)));
        uint32_t* dst = (uint32_t*)(Ff + (size_t)tid * 18);
#pragma unroll
        for (int q = 0; q < 9; ++q) dst[q] = pk.w[q];
    } else if (tid < NPX + NTH) {
        int e  = tid - NPX;
        int k  = e % 1728;
        int fi = e / 1728;
        int f  = fi & 63;
        int i  = fi >> 6;
        int j  = k / 576;
        int q  = k - j * 576;
        int c  = q / 18;
        int m  = q - c * 18;
        int base = ((f * 32 + c) * 3 + i) * 3 + j;           // (F,C,3,3) flat
        float v = (m < 17) ? wspl[base] * cp[base * 17 + m] : wsil[base];
        th[e] = (_Float16)v;
    }
}

// GEMM main: block = 128 thr (2 waves) = 64 px (one output row) x 64 f.
// grid (256 px-rows, 3 i-groups). K per block = 1728, chunks of 64.
// wave wv: px 32*wv..32*wv+31, both f-halves (2 acc tiles, A read once/step).
// LDS rows padded to 72 halves (144 B): 16B-aligned b128, spread banks.
// DOUBLE-BUFFERED: one __syncthreads per chunk (write buf[cur] -> barrier ->
// compute buf[cur]; readers of buf[cur^1] finished before the PREVIOUS
// barrier, so the next iteration's write to it is safe). Next chunk's global
// loads are issued AFTER the barrier so they fly under ds_read+MFMA and are
// only waited (fine-grained vmcnt) at the next iteration's ds_write.
__global__ __launch_bounds__(128) void kan_main(
    const _Float16* __restrict__ Ff, const _Float16* __restrict__ th,
    const float* __restrict__ bias, float* __restrict__ out)
{
    __shared__ _Float16 lA[2][64 * 72];            // 2 x 9216 B
    __shared__ _Float16 lB[2][64 * 72];            // 2 x 9216 B

    const int bx = blockIdx.x;                     // b = bx>>6, ho = bx&63
    const int i  = blockIdx.y;                     // 0..2
    const int b  = bx >> 6;
    const int ho = bx & 63;
    const int tid  = threadIdx.x;
    const int wv   = tid >> 6;
    const int lane = tid & 63;
    const int spx   = tid >> 1;                    // staging row 0..63
    const int shalf = tid & 1;

    const size_t Abase = (size_t)((b * 66 + ho + i) * 66) * 576;
    const size_t Bbase = (size_t)(i * 64 + spx) * 1728;

    uint4 pfA0, pfA1, pfA2, pfA3, pfB0, pfB1, pfB2, pfB3;
#define LOADCH(ch)                                                             \
    {                                                                          \
        int j_  = (ch) / 9;                                                    \
        int qo_ = ((ch) - j_ * 9) * 64;                                        \
        const uint4* ga = (const uint4*)(Ff + Abase + (size_t)(spx + j_) * 576 \
                                         + qo_ + shalf * 32);                  \
        pfA0 = ga[0]; pfA1 = ga[1]; pfA2 = ga[2]; pfA3 = ga[3];                \
        const uint4* gb = (const uint4*)(th + Bbase + (ch) * 64 + shalf * 32); \
        pfB0 = gb[0]; pfB1 = gb[1]; pfB2 = gb[2]; pfB3 = gb[3];                \
    }

    LOADCH(0)

    const int r31 = lane & 31, kh = lane >> 5;
    f32x16 acc0, acc1;
    {
        float b0v = (i == 1) ? bias[r31] : 0.0f;
        float b1v = (i == 1) ? bias[32 + r31] : 0.0f;
#pragma unroll
        for (int r = 0; r < 16; ++r) { acc0[r] = b0v; acc1[r] = b1v; }
    }

    const int aoff  = (wv * 32 + r31) * 72 + kh * 8;   // fragment read offsets
    const int boff0 = r31 * 72 + kh * 8;
    const int boff1 = (32 + r31) * 72 + kh * 8;
    char* wbA = (char*)lA[0] + spx * 144 + shalf * 64; // staging write base
    char* wbB = (char*)lB[0] + spx * 144 + shalf * 64;

    int cur = 0;
    for (int ch = 0; ch < 27; ++ch) {
        uint4* wA = (uint4*)(wbA + cur * 9216);
        uint4* wB = (uint4*)(wbB + cur * 9216);
        wA[0] = pfA0; wA[1] = pfA1; wA[2] = pfA2; wA[3] = pfA3;
        wB[0] = pfB0; wB[1] = pfB1; wB[2] = pfB2; wB[3] = pfB3;
        __syncthreads();                           // writes of buf[cur] visible
        if (ch < 26) LOADCH(ch + 1)                // in flight under compute
        const _Float16* pa  = lA[cur] + aoff;
        const _Float16* pb0 = lB[cur] + boff0;
        const _Float16* pb1 = lB[cur] + boff1;
#pragma unroll
        for (int s = 0; s < 4; ++s) {
            half8 a  = *(const half8*)(pa  + s * 16);
            half8 b0 = *(const half8*)(pb0 + s * 16);
            half8 b1 = *(const half8*)(pb1 + s * 16);
            acc0 = __builtin_amdgcn_mfma_f32_32x32x16_f16(a, b0, acc0, 0, 0, 0);
            acc1 = __builtin_amdgcn_mfma_f32_32x32x16_f16(a, b1, acc1, 0, 0, 0);
        }
        cur ^= 1;
    }
#undef LOADCH

    // C/D layout (verified): col = lane&31, row = (reg&3)+8*(reg>>2)+4*(lane>>5)
    float* orow = out + ((size_t)(b * 64 + ho) * 64) * 64;
#pragma unroll
    for (int r = 0; r < 16; ++r) {
        int row = (r & 3) + 8 * (r >> 2) + 4 * kh;
        int wo  = wv * 32 + row;
        atomicAdd(orow + wo * 64 + r31,      acc0[r]);
        atomicAdd(orow + wo * 64 + 32 + r31, acc1[r]);
    }
}

extern "C" void kernel_launch(void* const* d_in, const int* in_sizes, int n_in,
                              void* d_out, int out_size, void* d_ws, size_t ws_size,
                              hipStream_t stream) {
    const float* x    = (const float*)d_in[0];
    const float* cp   = (const float*)d_in[1];
    const float* wspl = (const float*)d_in[2];
    const float* wsil = (const float*)d_in[3];
    const float* bias = (const float*)d_in[4];
    float* out = (float*)d_out;

    uint8_t* ws = (uint8_t*)d_ws;
    _Float16* Ff = (_Float16*)ws;
    _Float16* th = (_Float16*)(ws + TH_OFF_BYTES);

    kan_prep<<<PREP_BLOCKS, 256, 0, stream>>>(x, cp, wspl, wsil, Ff, th);
    hipMemsetAsync(d_out, 0, (size_t)out_size * 4, stream);

    dim3 grid(256, 3);
    kan_main<<<grid, 128, 0, stream>>>(Ff, th, bias, out);
}